// Round 2
// baseline (3247.407 us; speedup 1.0000x reference)
//
#include <hip/hip_runtime.h>
#include <string.h>

#define BB 64
#define TS 2000
#define NN (TS*160)
#define FR 160
#define CF 128
#define TT 40
#define NTH 320
#define EPS_LOG 1.52587890625e-05f   // 2^-16

// repacked weight layout in d_ws (float4 index offsets)
#define R1F_OFF4 0        // 10240 f4  : conv1f weights, [c4][j*2+half][oq]
#define R1T_OFF4 10240    // 3200 f4   : conv1t weights (e4 groups 0..9)
#define R1TREM_OFF2 26880 // 160 f2    : conv1t e=40 remainder, [o] = (tap0,tap1)
#define R2_OFF4 13520     // 12800 f4  : conv2 weights

// static LDS layout (float offsets) — s_hid ALIASES s_feat/s_tenv (written
// only after all feat/tenv reads complete; guarded by __syncthreads)
#define SM_FEAT 0                   // [42][128] = 5376 floats
#define SM_TENV 5376                // [42][44]  = 1848 floats
#define SM_HID  0                   // [41][160] = 6560 floats (alias)
#define SM_W    7224                // 2 x 640 float4 = 5120 floats
#define SM_FLOATS 12344             // 49376 bytes < 64KB

__global__ void repack_kernel(const float* __restrict__ W1f,
                              const float* __restrict__ W1t,
                              const float* __restrict__ W2,
                              float* __restrict__ ws) {
    int i = blockIdx.x * 256 + threadIdx.x;
    float4* ws4 = (float4*)ws;
    float2* ws2 = (float2*)ws;
    const float4* W1f4 = (const float4*)W1f;
    const float2* W1t2 = (const float2*)W1t;
    const float4* W24  = (const float4*)W2;
    if (i < 10240) {
        int r = i;
        int c4 = r / 320, rem = r % 320, q8 = rem / 40, oq = rem % 40;
        int j = q8 >> 1, half = q8 & 1, o = oq * 4 + j;
        ws4[R1F_OFF4 + r] = W1f4[o * 64 + c4 * 2 + half];
    } else if (i < 10240 + 3200) {
        int r = i - 10240;
        int e4 = r / 320, rem = r % 320, q8 = rem / 40, oq = rem % 40;
        int j = q8 >> 1, half = q8 & 1, o = oq * 4 + j;
        float2 a = W1t2[o * 41 + e4 * 4 + half * 2];
        float2 b = W1t2[o * 41 + e4 * 4 + half * 2 + 1];
        ws4[R1T_OFF4 + r] = make_float4(a.x, a.y, b.x, b.y);
    } else if (i < 10240 + 3200 + 160) {
        int o = i - (10240 + 3200);
        ws2[R1TREM_OFF2 + o] = W1t2[o * 41 + 40];
    } else if (i < 10240 + 3200 + 160 + 12800) {
        int r = i - (10240 + 3200 + 160);
        int c4 = r / 320, rem = r % 320, q8 = rem / 40, oq = rem % 40;
        int j = q8 >> 1, half = q8 & 1, o = oq * 4 + j;
        ws4[R2_OFF4 + r] = W24[o * 80 + c4 * 2 + half];
    }
}

__global__ __launch_bounds__(NTH) void td_main(
    const float* __restrict__ x,
    const float* __restrict__ feat,
    const float* __restrict__ ws,
    const float* __restrict__ b1f,
    const float* __restrict__ b1t,
    const float* __restrict__ b2,
    float* __restrict__ out)
{
    __shared__ float sm[SM_FLOATS];
    float*  s_feat = sm + SM_FEAT;   // rows r=0..41 <-> t = t0-2+r
    float*  s_tenv = sm + SM_TENV;   // rows r=0..41, cols 0..40 (stride 44)
    float*  s_hid  = sm + SM_HID;    // rows h=0..40 <-> t = t0-1+h (ALIAS)
    float4* s_w    = (float4*)(sm + SM_W);

    const int tid = threadIdx.x;
    const int b   = blockIdx.y;
    const int t0  = blockIdx.x * TT;

    const float4* x4    = (const float4*)x;
    const float4* feat4 = (const float4*)feat;
    const float4* ws4   = (const float4*)ws;
    const float2* ws2   = (const float2*)ws;

    // ---- stage features (42 rows x 128) + conv1f weight chunk 0 ----
    for (int idx = tid; idx < 42 * 32; idx += NTH) {
        int r = idx >> 5, c4 = idx & 31;
        int t = t0 - 2 + r;
        float4 v = make_float4(0.f, 0.f, 0.f, 0.f);
        if (t >= 0) v = feat4[(size_t)(b * TS + t) * 32 + c4];
        *(float4*)&s_feat[r * CF + c4 * 4] = v;
    }
    s_w[tid]       = ws4[R1F_OFF4 + tid];
    s_w[320 + tid] = ws4[R1F_OFF4 + 320 + tid];

    // ---- envelope e values ----
    for (int idx = tid; idx < 42 * 40; idx += NTH) {
        int r = idx / 40, g = idx - r * 40;
        int t = t0 - 2 + r;
        float e = 0.f;
        if (t >= 0) {
            float4 v = x4[((size_t)b * NN + (size_t)t * 160 + g * 4) >> 2];
            float m = 0.25f * (fabsf(v.x) + fabsf(v.y) + fabsf(v.z) + fabsf(v.w));
            e = __logf(m + EPS_LOG);
        }
        s_tenv[r * 44 + g] = e;
    }
    __syncthreads();

    // ---- per-row mean, subtract, store avg in col 40 ----
    if (tid < 42) {
        float s = 0.f;
        for (int g = 0; g < 40; ++g) s += s_tenv[tid * 44 + g];
        float avg = s * 0.025f;
        for (int g = 0; g < 40; ++g) s_tenv[tid * 44 + g] -= avg;
        s_tenv[tid * 44 + 40] = avg;
    }
    __syncthreads();

    const int oq = tid % 40;
    const int hg = tid / 40;
    const int o0 = oq * 4;

    // =========== stage B: hidden = leaky(conv1f + conv1t) ===========
    const int HB0 = hg * 6;
    float accB[6][4];
    {
        float bias[4];
#pragma unroll
        for (int j = 0; j < 4; ++j) bias[j] = b1f[o0 + j] + b1t[o0 + j];
#pragma unroll
        for (int i = 0; i < 6; ++i)
#pragma unroll
            for (int j = 0; j < 4; ++j) accB[i][j] = bias[j];
    }

    // conv over features: 16 chunks x (2 c4-groups)
#pragma unroll 2
    for (int ci = 0; ci < 16; ++ci) {
        int par = ci & 1;
        float4 nx0, nx1;
        bool has_next = (ci + 1 < 16);
        if (has_next) {
            nx0 = ws4[R1F_OFF4 + (ci + 1) * 640 + tid];
            nx1 = ws4[R1F_OFF4 + (ci + 1) * 640 + 320 + tid];
        } else {
            nx0 = ws4[R1T_OFF4 + tid];
            nx1 = ws4[R1T_OFF4 + 320 + tid];
        }
#pragma unroll
        for (int cc = 0; cc < 2; ++cc) {
            int c4 = ci * 2 + cc;
            float4 f[7];
#pragma unroll
            for (int i = 0; i < 7; ++i) {
                int rr = HB0 + i; rr = rr > 41 ? 41 : rr;
                f[i] = *(const float4*)&s_feat[rr * CF + c4 * 4];
            }
            const float4* wbase = &s_w[par * 640 + cc * 320];
#pragma unroll
            for (int j = 0; j < 4; ++j) {
                float4 wa = wbase[j * 80 + oq];
                float4 wb = wbase[j * 80 + 40 + oq];
#pragma unroll
                for (int i = 0; i < 6; ++i) {
                    accB[i][j] += f[i].x * wa.x + f[i + 1].x * wa.y
                                + f[i].y * wa.z + f[i + 1].y * wa.w
                                + f[i].z * wb.x + f[i + 1].z * wb.y
                                + f[i].w * wb.z + f[i + 1].w * wb.w;
                }
            }
        }
        s_w[(par ^ 1) * 640 + tid]       = nx0;
        s_w[(par ^ 1) * 640 + 320 + tid] = nx1;
        __syncthreads();
    }

    // conv over tenv: 5 chunks (e4 = 0..9)
#pragma unroll 2
    for (int ci = 0; ci < 5; ++ci) {
        int par = ci & 1;
        float4 nx0, nx1;
        bool has_next = (ci + 1 < 5);
        if (has_next) {
            nx0 = ws4[R1T_OFF4 + (ci + 1) * 640 + tid];
            nx1 = ws4[R1T_OFF4 + (ci + 1) * 640 + 320 + tid];
        } else {
            nx0 = ws4[R2_OFF4 + tid];
            nx1 = ws4[R2_OFF4 + 320 + tid];
        }
#pragma unroll
        for (int cc = 0; cc < 2; ++cc) {
            int e4 = ci * 2 + cc;
            float4 f[7];
#pragma unroll
            for (int i = 0; i < 7; ++i) {
                int rr = HB0 + i; rr = rr > 41 ? 41 : rr;
                f[i] = *(const float4*)&s_tenv[rr * 44 + e4 * 4];
            }
            const float4* wbase = &s_w[par * 640 + cc * 320];
#pragma unroll
            for (int j = 0; j < 4; ++j) {
                float4 wa = wbase[j * 80 + oq];
                float4 wb = wbase[j * 80 + 40 + oq];
#pragma unroll
                for (int i = 0; i < 6; ++i) {
                    accB[i][j] += f[i].x * wa.x + f[i + 1].x * wa.y
                                + f[i].y * wa.z + f[i + 1].y * wa.w
                                + f[i].z * wb.x + f[i + 1].z * wb.y
                                + f[i].w * wb.z + f[i + 1].w * wb.w;
                }
            }
        }
        s_w[(par ^ 1) * 640 + tid]       = nx0;
        s_w[(par ^ 1) * 640 + 320 + tid] = nx1;
        __syncthreads();
    }

    // tenv remainder (e = 40, the avg channel)
    {
        float fs[7];
#pragma unroll
        for (int i = 0; i < 7; ++i) {
            int rr = HB0 + i; rr = rr > 41 ? 41 : rr;
            fs[i] = s_tenv[rr * 44 + 40];
        }
#pragma unroll
        for (int j = 0; j < 4; ++j) {
            float2 w = ws2[R1TREM_OFF2 + o0 + j];
#pragma unroll
            for (int i = 0; i < 6; ++i) accB[i][j] += fs[i] * w.x + fs[i + 1] * w.y;
        }
    }

    // all feat/tenv reads done -> safe to overwrite the aliased region with hid
    __syncthreads();

    // leaky relu + store hidden (zero the causal pad row t=-1)
#pragma unroll
    for (int i = 0; i < 6; ++i) {
        int h = HB0 + i;
        if (h < 41) {
            int th = t0 - 1 + h;
            float4 v;
#pragma unroll
            for (int j = 0; j < 4; ++j) {
                float a = accB[i][j];
                a = a >= 0.f ? a : 0.2f * a;
                ((float*)&v)[j] = (th >= 0) ? a : 0.f;
            }
            *(float4*)&s_hid[h * FR + o0] = v;
        }
    }
    __syncthreads();

    // =========== stage C: y = exp(conv2(hidden)+b2) * x ===========
    const int HC0 = hg * 5;
    float accC[5][4];
#pragma unroll
    for (int j = 0; j < 4; ++j) {
        float bj = b2[o0 + j];
#pragma unroll
        for (int i = 0; i < 5; ++i) accC[i][j] = bj;
    }

#pragma unroll 2
    for (int ci = 0; ci < 20; ++ci) {
        int par = (ci + 1) & 1;   // chunk0 lives in buffer 1 (staged during conv1t tail)
        float4 nx0, nx1;
        bool has_next = (ci + 1 < 20);
        if (has_next) {
            nx0 = ws4[R2_OFF4 + (ci + 1) * 640 + tid];
            nx1 = ws4[R2_OFF4 + (ci + 1) * 640 + 320 + tid];
        }
#pragma unroll
        for (int cc = 0; cc < 2; ++cc) {
            int c4 = ci * 2 + cc;
            float4 f[6];
#pragma unroll
            for (int i = 0; i < 6; ++i)
                f[i] = *(const float4*)&s_hid[(HC0 + i) * FR + c4 * 4];
            const float4* wbase = &s_w[par * 640 + cc * 320];
#pragma unroll
            for (int j = 0; j < 4; ++j) {
                float4 wa = wbase[j * 80 + oq];
                float4 wb = wbase[j * 80 + 40 + oq];
#pragma unroll
                for (int i = 0; i < 5; ++i) {
                    accC[i][j] += f[i].x * wa.x + f[i + 1].x * wa.y
                                + f[i].y * wa.z + f[i + 1].y * wa.w
                                + f[i].z * wb.x + f[i + 1].z * wb.y
                                + f[i].w * wb.z + f[i + 1].w * wb.w;
                }
            }
        }
        if (has_next) {
            s_w[(par ^ 1) * 640 + tid]       = nx0;
            s_w[(par ^ 1) * 640 + 320 + tid] = nx1;
            __syncthreads();
        }
    }

    // epilogue: alpha = exp(acc), y = alpha * x, f32 store
#pragma unroll
    for (int i = 0; i < 5; ++i) {
        int w = HC0 + i;
        int t = t0 + w;
        size_t base = (size_t)b * NN + (size_t)t * 160 + o0;
        float4 xv = x4[base >> 2];
        float4 yv;
        yv.x = __expf(accC[i][0]) * xv.x;
        yv.y = __expf(accC[i][1]) * xv.y;
        yv.z = __expf(accC[i][2]) * xv.z;
        yv.w = __expf(accC[i][3]) * xv.w;
        *(float4*)&out[base] = yv;
    }
}

extern "C" void kernel_launch(void* const* d_in, const int* in_sizes, int n_in,
                              void* d_out, int out_size, void* d_ws, size_t ws_size,
                              hipStream_t stream) {
    const float* x    = (const float*)d_in[0];
    const float* feat = (const float*)d_in[1];
    const float* W1f  = (const float*)d_in[2];
    const float* b1f  = (const float*)d_in[3];
    const float* W1t  = (const float*)d_in[4];
    const float* b1t  = (const float*)d_in[5];
    const float* W2   = (const float*)d_in[6];
    const float* b2   = (const float*)d_in[7];
    float* out = (float*)d_out;
    float* ws  = (float*)d_ws;

    repack_kernel<<<(26400 + 255) / 256, 256, 0, stream>>>(W1f, W1t, W2, ws);
    td_main<<<dim3(TS / TT, BB), NTH, 0, stream>>>(x, feat, ws, b1f, b1t, b2, out);
}

// Round 3
// 146.878 us; speedup vs baseline: 22.1095x; 22.1095x over previous
//
#include <hip/hip_runtime.h>

typedef __attribute__((ext_vector_type(8))) short short8;
typedef __attribute__((ext_vector_type(4))) float f32x4;

#define BB 64
#define TS 2000
#define NN (TS*160)
#define MB 48
#define TB 42            // ceil(2000/48)
#define NTH 256
#define EPS_LOG 1.52587890625e-05f   // 2^-16

// ws layout: ushort (bf16) region then float region
#define W1F_U 0          // 40960 ushorts: [tap][ct10][kp16][col16][8]
#define W1T_U 40960      // 20480 ushorts: [tap][ct10][kp8][col16][8] (k>=41 zero)
#define W2_U  61440      // 51200 ushorts: [tap][ct10][kp20][col16][8]
#define B1C_F 56320      // float idx: b1f+b1t (160)
#define B2C_F 56480      // float idx: b2 (160)

__device__ __forceinline__ unsigned short f2bf(float f) {
    union { float f; unsigned u; } v; v.f = f;
    unsigned r = v.u + 0x7FFF + ((v.u >> 16) & 1);   // RNE
    return (unsigned short)(r >> 16);
}

__global__ void repack(const float* __restrict__ W1f, const float* __restrict__ b1f,
                       const float* __restrict__ W1t, const float* __restrict__ b1t,
                       const float* __restrict__ W2,  const float* __restrict__ b2,
                       void* wsv) {
    unsigned short* wu = (unsigned short*)wsv;
    float* wf = (float*)wsv;
    int n = blockIdx.x * 256 + threadIdx.x;
    if (n < 40960) {                       // W1f
        int tap = n / 20480, m = n % 20480;
        int ct = m / 2048, m2 = m % 2048;
        int kp = m2 / 128, col = (m2 % 128) / 8, i = m2 % 8;
        int o = ct * 16 + col, c = kp * 8 + i;
        wu[W1F_U + n] = f2bf(W1f[(o * 128 + c) * 2 + tap]);
    } else if (n < 61440) {                // W1t (K padded to 64)
        int r = n - 40960;
        int tap = r / 10240, m = r % 10240;
        int ct = m / 1024, m2 = m % 1024;
        int kp = m2 / 128, col = (m2 % 128) / 8, i = m2 % 8;
        int o = ct * 16 + col, c = kp * 8 + i;
        wu[W1T_U + r] = (c < 41) ? f2bf(W1t[(o * 41 + c) * 2 + tap]) : (unsigned short)0;
    } else if (n < 112640) {               // W2
        int r = n - 61440;
        int tap = r / 25600, m = r % 25600;
        int ct = m / 2560, m2 = m % 2560;
        int kp = m2 / 128, col = (m2 % 128) / 8, i = m2 % 8;
        int o = ct * 16 + col, c = kp * 8 + i;
        wu[W2_U + r] = f2bf(W2[(o * 160 + c) * 2 + tap]);
    } else if (n < 112800) {               // b1 combined
        int o = n - 112640;
        wf[B1C_F + o] = b1f[o] + b1t[o];
    } else if (n < 112960) {               // b2 copy
        int o = n - 112800;
        wf[B2C_F + o] = b2[o];
    }
}

__global__ __launch_bounds__(NTH, 3) void td_main(
    const float* __restrict__ x,
    const float* __restrict__ feat,
    const unsigned short* __restrict__ wu,
    const float* __restrict__ wf,
    float* __restrict__ out)
{
    // LDS: strides chosen so row-stride bytes ≡ 16 (mod 128) -> min bank aliasing
    __shared__ __align__(16) unsigned short s_feat[65 * 136]; // slot r <-> t=t0-17+r
    __shared__ __align__(16) unsigned short s_tenv[65 * 72];  // cols 0..40 data, 41..63 zero
    __shared__ __align__(16) unsigned short s_hid [64 * 168]; // slot h <-> t=t0-16+h

    const int tid = threadIdx.x;
    const int b   = blockIdx.y;
    const int t0  = blockIdx.x * MB;

    // ---- stage features -> bf16 LDS ----
    const float4* feat4 = (const float4*)feat;
    for (int idx = tid; idx < 65 * 32; idx += NTH) {
        int r = idx >> 5, c4 = idx & 31;
        int t = t0 - 17 + r;
        float4 v = make_float4(0.f, 0.f, 0.f, 0.f);
        if (t >= 0 && t < TS) v = feat4[((size_t)b * TS + t) * 32 + c4];
        ushort4 h;
        h.x = f2bf(v.x); h.y = f2bf(v.y); h.z = f2bf(v.z); h.w = f2bf(v.w);
        *(ushort4*)&s_feat[r * 136 + c4 * 4] = h;
    }

    // ---- envelope -> tenv (half-wave per row, shuffle reduce) ----
    {
        const int hw = tid >> 5;     // 0..7
        const int hl = tid & 31;
        for (int r = hw; r < 65; r += 8) {
            int t = t0 - 17 + r;
            if (t >= 0 && t < TS) {
                const float4* xr = (const float4*)(x + (size_t)b * NN + (size_t)t * 160);
                float4 v = xr[hl];
                float e1 = __logf(0.25f * (fabsf(v.x) + fabsf(v.y) + fabsf(v.z) + fabsf(v.w)) + EPS_LOG);
                float e2 = 0.f;
                if (hl < 8) {
                    float4 u = xr[hl + 32];
                    e2 = __logf(0.25f * (fabsf(u.x) + fabsf(u.y) + fabsf(u.z) + fabsf(u.w)) + EPS_LOG);
                }
                float s = e1 + e2;
#pragma unroll
                for (int m = 16; m; m >>= 1) s += __shfl_xor(s, m, 32);
                float avg = s * 0.025f;
                s_tenv[r * 72 + hl] = f2bf(e1 - avg);
                if (hl < 8)        s_tenv[r * 72 + 32 + hl] = f2bf(e2 - avg);
                else if (hl == 8)  s_tenv[r * 72 + 40]      = f2bf(avg);
                else               s_tenv[r * 72 + 32 + hl] = 0;   // cols 41..63 zero
            } else {
                s_tenv[r * 72 + hl]      = 0;
                s_tenv[r * 72 + 32 + hl] = 0;
            }
        }
    }
    __syncthreads();

    const int wid  = tid >> 6;
    const int lane = tid & 63;
    const int lr   = lane & 15;   // A row within tile / D col
    const int lk   = lane >> 4;   // k-group / D row-group

    // =========== stage B: hid = leaky(conv1f + conv1t), tiles at t0-16+16*wid ===========
    {
        const int h0 = wid * 16;
        short8 fa0[4], fa1[4], ea0[2], ea1[2];
        const unsigned short* f0 = &s_feat[(h0 + lr) * 136 + lk * 8];
#pragma unroll
        for (int s = 0; s < 4; ++s) {
            fa0[s] = *(const short8*)(f0 + 32 * s);          // tap0: feat[t-1]
            fa1[s] = *(const short8*)(f0 + 136 + 32 * s);    // tap1: feat[t]
        }
        const unsigned short* e0 = &s_tenv[(h0 + lr) * 72 + lk * 8];
#pragma unroll
        for (int s = 0; s < 2; ++s) {
            ea0[s] = *(const short8*)(e0 + 32 * s);
            ea1[s] = *(const short8*)(e0 + 72 + 32 * s);
        }

        for (int ct = 0; ct < 10; ++ct) {
            float bias = wf[B1C_F + ct * 16 + lr];
            f32x4 acc = {0.f, 0.f, 0.f, 0.f};
            const unsigned short* bf0 = wu + W1F_U + ct * 2048 + lk * 128 + lr * 8;
            const unsigned short* bt0 = wu + W1T_U + ct * 1024 + lk * 128 + lr * 8;
#pragma unroll
            for (int s = 0; s < 4; ++s) {
                short8 w0 = *(const short8*)(bf0 + s * 512);
                acc = __builtin_amdgcn_mfma_f32_16x16x32_bf16(fa0[s], w0, acc, 0, 0, 0);
            }
#pragma unroll
            for (int s = 0; s < 4; ++s) {
                short8 w1 = *(const short8*)(bf0 + 20480 + s * 512);
                acc = __builtin_amdgcn_mfma_f32_16x16x32_bf16(fa1[s], w1, acc, 0, 0, 0);
            }
#pragma unroll
            for (int s = 0; s < 2; ++s) {
                short8 w0 = *(const short8*)(bt0 + s * 512);
                acc = __builtin_amdgcn_mfma_f32_16x16x32_bf16(ea0[s], w0, acc, 0, 0, 0);
                short8 w1 = *(const short8*)(bt0 + 10240 + s * 512);
                acc = __builtin_amdgcn_mfma_f32_16x16x32_bf16(ea1[s], w1, acc, 0, 0, 0);
            }
#pragma unroll
            for (int j = 0; j < 4; ++j) {
                float v = acc[j] + bias;
                v = v >= 0.f ? v : 0.2f * v;
                s_hid[(h0 + lk * 4 + j) * 168 + ct * 16 + lr] = f2bf(v);
            }
        }
    }
    __syncthreads();

    // =========== stage C: out = exp(conv2(hid)+b2) * x, tiles at t0+16*wid ===========
    if (wid < 3) {
        short8 ha0[5], ha1[5];
        const unsigned short* hb = &s_hid[(15 + wid * 16 + lr) * 168 + lk * 8];
#pragma unroll
        for (int s = 0; s < 5; ++s) {
            ha0[s] = *(const short8*)(hb + 32 * s);          // tap0: hid[t-1]
            ha1[s] = *(const short8*)(hb + 168 + 32 * s);    // tap1: hid[t]
        }
        for (int ct = 0; ct < 10; ++ct) {
            float b2v = wf[B2C_F + ct * 16 + lr];
            f32x4 acc = {0.f, 0.f, 0.f, 0.f};
            const unsigned short* b2p = wu + W2_U + ct * 2560 + lk * 128 + lr * 8;
#pragma unroll
            for (int s = 0; s < 5; ++s) {
                short8 w0 = *(const short8*)(b2p + s * 512);
                acc = __builtin_amdgcn_mfma_f32_16x16x32_bf16(ha0[s], w0, acc, 0, 0, 0);
            }
#pragma unroll
            for (int s = 0; s < 5; ++s) {
                short8 w1 = *(const short8*)(b2p + 25600 + s * 512);
                acc = __builtin_amdgcn_mfma_f32_16x16x32_bf16(ha1[s], w1, acc, 0, 0, 0);
            }
#pragma unroll
            for (int j = 0; j < 4; ++j) {
                int t = t0 + wid * 16 + lk * 4 + j;
                if (t < TS) {
                    size_t off = (size_t)b * NN + (size_t)t * 160 + ct * 16 + lr;
                    out[off] = __expf(acc[j] + b2v) * x[off];
                }
            }
        }
    }
}

extern "C" void kernel_launch(void* const* d_in, const int* in_sizes, int n_in,
                              void* d_out, int out_size, void* d_ws, size_t ws_size,
                              hipStream_t stream) {
    const float* x    = (const float*)d_in[0];
    const float* feat = (const float*)d_in[1];
    const float* W1f  = (const float*)d_in[2];
    const float* b1f  = (const float*)d_in[3];
    const float* W1t  = (const float*)d_in[4];
    const float* b1t  = (const float*)d_in[5];
    const float* W2   = (const float*)d_in[6];
    const float* b2   = (const float*)d_in[7];
    float* out = (float*)d_out;

    repack<<<(112960 + 255) / 256, 256, 0, stream>>>(W1f, b1f, W1t, b1t, W2, b2, d_ws);
    td_main<<<dim3(TB, BB), NTH, 0, stream>>>(
        x, feat, (const unsigned short*)d_ws, (const float*)d_ws, out);
}